// Round 2
// baseline (28062.064 us; speedup 1.0000x reference)
//
#include <hip/hip_runtime.h>
#include <math.h>

// ---------------- constants ----------------
static constexpr int TT   = 1026;   // transformer length
static constexpr int T_S1 = 8216;
static constexpr int T_S2 = 49302;
static constexpr int T_S3 = 246515;
static constexpr int T_S4 = 986064;

static constexpr int NCH    = 8;                 // stage-4 time chunks
static constexpr int LC     = T_S4 / NCH;        // 123258
static constexpr int LE_MAX = LC + 8;            // chunk + 8-frame halo

// workspace offsets (floats). Peak = 47,330,880 fl = 189.3 MB < 256 MiB.
// Frontend/transformer region [0 .. 8,469,632):
static constexpr size_t O_X0  = 0;
static constexpr size_t O_XQ  = 262144;
static constexpr size_t O_XU  = 524288;    // (512,1026)
static constexpr size_t O_Z   = 1049600;   // (1026,512)
static constexpr size_t O_HN  = 1574912;
static constexpr size_t O_QKV = 2100224;   // (1026,1536)
static constexpr size_t O_AO  = 3676160;   // (1026,512)
static constexpr size_t O_FF  = 4201472;   // (1026,2048)
static constexpr size_t O_COS = 6302720;   // (1026,32)
static constexpr size_t O_SIN = 6335552;
static constexpr size_t O_ZT  = 6368384;   // (1026,512)
static constexpr size_t O_ZC  = 6893696;   // (512,1026)
static constexpr size_t O_D0  = 7419008;   // (1024,1026) ends 8,469,632
// Conv-stage overlays (temporal liveness verified):
static constexpr size_t O_Z1  = 8469632;   // (512,8216)  ends 12,676,224 ; live convtr1..convtr2
static constexpr size_t O_V1  = 12676224;  // (256,8216)  ends 14,779,520
static constexpr size_t O_Z2  = 31553920;  // (256,49302) ends 44,175,232 ; live convtr2..convtr3
static constexpr size_t O_V2  = 0;         // (128,49302) ends  6,310,656 ; frontend dead by then
static constexpr size_t O_Z3  = 0;         // (128,246515) ends 31,553,920 ; written after v2 dead
static constexpr size_t O_V3  = 31553920;  // (64,246515)  ends 47,330,880 ; after z2 dead  <-- PEAK
static constexpr size_t O_Z4C = 31553920;  // (64,LE_MAX)  ends 39,442,944 ; after v3 dead
static constexpr size_t O_VAC = 39442944;  // (32,LE_MAX)  ends 43,387,456

// ---------------- elementwise ----------------
__global__ __launch_bounds__(256) void embed_k(const float* __restrict__ lat,
    const float* __restrict__ sd, const float* __restrict__ mn, float* __restrict__ y)
{
    int i = blockIdx.x * 256 + threadIdx.x;
    if (i >= 512 * 512) return;
    int c = i >> 9;
    y[i] = lat[i] * sd[c] + mn[c];
}

__global__ __launch_bounds__(256) void elu_ip(float* __restrict__ x, int n)
{
    int i = blockIdx.x * 256 + threadIdx.x;
    if (i < n) {
        float v = x[i];
        x[i] = v > 0.f ? v : __expf(v) - 1.f;
    }
}

__global__ __launch_bounds__(256) void rope_tables(float* __restrict__ cs, float* __restrict__ sn)
{
    int idx = blockIdx.x * 256 + threadIdx.x;
    if (idx >= TT * 32) return;
    int i = idx & 31;
    int t = idx >> 5;
    float fr = expf(-(float)i * (logf(10000.f) / 32.f));
    float ang = (float)t * fr;
    cs[idx] = cosf(ang);
    sn[idx] = sinf(ang);
}

__global__ __launch_bounds__(256) void rope_apply(float* __restrict__ qkv,
    const float* __restrict__ cs, const float* __restrict__ sn)
{
    int idx = blockIdx.x * 256 + threadIdx.x;
    if (idx >= TT * 8 * 32) return;
    int i = idx & 31;
    int h = (idx >> 5) & 7;
    int t = idx >> 8;
    float c = cs[t * 32 + i], s = sn[t * 32 + i];
    size_t base = (size_t)t * 1536 + h * 64 + 2 * i;
    float re = qkv[base], im = qkv[base + 1];
    qkv[base]     = re * c - im * s;
    qkv[base + 1] = re * s + im * c;
    base += 512;
    re = qkv[base]; im = qkv[base + 1];
    qkv[base]     = re * c - im * s;
    qkv[base + 1] = re * s + im * c;
}

__global__ __launch_bounds__(256) void transpose_k(const float* __restrict__ in,
    float* __restrict__ out, int R, int C)
{   // in (R,C) row-major -> out (C,R) row-major
    __shared__ float tile[32][33];
    int c0 = blockIdx.x * 32, r0 = blockIdx.y * 32;
    int tx = threadIdx.x & 31, ty = threadIdx.x >> 5;
    for (int dy = ty; dy < 32; dy += 8) {
        int r = r0 + dy, c = c0 + tx;
        tile[dy][tx] = (r < R && c < C) ? in[(size_t)r * C + c] : 0.f;
    }
    __syncthreads();
    for (int dy = ty; dy < 32; dy += 8) {
        int c = c0 + dy, r = r0 + tx;
        if (c < C && r < R) out[(size_t)c * R + r] = tile[tx][dy];
    }
}

// ---------------- layernorm (D=512), one block per token ----------------
__global__ __launch_bounds__(256) void ln_kernel(const float* __restrict__ x,
    const float* __restrict__ w, const float* __restrict__ b, float* __restrict__ y)
{
    int t = blockIdx.x, tid = threadIdx.x;
    const float* xr = x + (size_t)t * 512;
    float v0 = xr[tid], v1 = xr[tid + 256];
    float s = v0 + v1, q = v0 * v0 + v1 * v1;
    for (int off = 32; off; off >>= 1) {
        s += __shfl_down(s, off);
        q += __shfl_down(q, off);
    }
    __shared__ float ss[4], qq[4], mb[2];
    int wid = tid >> 6, lane = tid & 63;
    if (lane == 0) { ss[wid] = s; qq[wid] = q; }
    __syncthreads();
    if (tid == 0) {
        float S = ss[0] + ss[1] + ss[2] + ss[3];
        float Q = qq[0] + qq[1] + qq[2] + qq[3];
        float m = S * (1.f / 512.f);
        float var = Q * (1.f / 512.f) - m * m;
        mb[0] = m;
        mb[1] = rsqrtf(var + 1e-5f);
    }
    __syncthreads();
    float m = mb[0], inv = mb[1];
    y[(size_t)t * 512 + tid]       = (v0 - m) * inv * w[tid] + b[tid];
    y[(size_t)t * 512 + tid + 256] = (v1 - m) * inv * w[tid + 256] + b[tid + 256];
}

// ---------------- NT GEMM: C[m,n] = sum_k A[m,k]*W[n,k], fused epilogues ----
// EPI 0: C = acc + bias ; 1: C = gelu(acc+bias) ; 2: C += ls[n]*(acc+bias)
template <int EPI>
__global__ __launch_bounds__(256) void gemm_nt(const float* __restrict__ A,
    const float* __restrict__ W, const float* __restrict__ bias,
    const float* __restrict__ ls, float* __restrict__ C, int M, int N, int K)
{
    __shared__ float As[16][68];
    __shared__ float Bs[16][68];
    int m0 = blockIdx.y * 64, n0 = blockIdx.x * 64;
    int tid = threadIdx.x;
    int tx = tid & 15, ty = tid >> 4;
    int arow = tid >> 2, acol = (tid & 3) * 4;
    float acc[4][4] = {};
    for (int k0 = 0; k0 < K; k0 += 16) {
        int am = m0 + arow;
        float4 av = make_float4(0.f, 0.f, 0.f, 0.f);
        if (am < M) av = *(const float4*)(A + (size_t)am * K + k0 + acol);
        float4 wv = *(const float4*)(W + (size_t)(n0 + arow) * K + k0 + acol);
        __syncthreads();
        As[acol + 0][arow] = av.x; As[acol + 1][arow] = av.y;
        As[acol + 2][arow] = av.z; As[acol + 3][arow] = av.w;
        Bs[acol + 0][arow] = wv.x; Bs[acol + 1][arow] = wv.y;
        Bs[acol + 2][arow] = wv.z; Bs[acol + 3][arow] = wv.w;
        __syncthreads();
#pragma unroll
        for (int kk = 0; kk < 16; kk++) {
            float4 a = *(const float4*)&As[kk][ty * 4];
            float4 b = *(const float4*)&Bs[kk][tx * 4];
            float aa[4] = {a.x, a.y, a.z, a.w};
            float bb[4] = {b.x, b.y, b.z, b.w};
#pragma unroll
            for (int i = 0; i < 4; i++)
#pragma unroll
                for (int j = 0; j < 4; j++)
                    acc[i][j] += aa[i] * bb[j];
        }
    }
#pragma unroll
    for (int i = 0; i < 4; i++) {
        int m = m0 + ty * 4 + i;
        if (m >= M) break;
#pragma unroll
        for (int j = 0; j < 4; j++) {
            int n = n0 + tx * 4 + j;
            float v = acc[i][j] + bias[n];
            size_t idx = (size_t)m * N + n;
            if (EPI == 0) C[idx] = v;
            else if (EPI == 1) C[idx] = 0.5f * v * (1.f + erff(v * 0.70710678118654752f));
            else C[idx] += ls[n] * v;
        }
    }
}

// ---------------- windowed causal attention, block per (t,h) ----------------
__global__ __launch_bounds__(256) void attn_kernel(const float* __restrict__ qkv,
    float* __restrict__ o)
{
    int t = blockIdx.x, h = blockIdx.y, tid = threadIdx.x;
    __shared__ float sq[64];
    __shared__ float sp[256];
    __shared__ float red[256];
    __shared__ float pacc[4][64];
    int klo = t - 249; if (klo < 0) klo = 0;
    int kc = t - klo + 1;
    if (tid < 64) sq[tid] = qkv[(size_t)t * 1536 + h * 64 + tid];
    __syncthreads();
    float sval = -3.0e38f;
    if (tid < kc) {
        const float* kr = qkv + (size_t)(klo + tid) * 1536 + 512 + h * 64;
        float d = 0.f;
#pragma unroll 8
        for (int i = 0; i < 64; i++) d += sq[i] * kr[i];
        sval = d * 0.125f;
    }
    red[tid] = sval;
    __syncthreads();
    for (int s2 = 128; s2 > 0; s2 >>= 1) {
        if (tid < s2) red[tid] = fmaxf(red[tid], red[tid + s2]);
        __syncthreads();
    }
    float m = red[0];
    __syncthreads();
    float p = (tid < kc) ? __expf(sval - m) : 0.f;
    sp[tid] = p;
    red[tid] = p;
    __syncthreads();
    for (int s2 = 128; s2 > 0; s2 >>= 1) {
        if (tid < s2) red[tid] += red[tid + s2];
        __syncthreads();
    }
    float inv = 1.f / red[0];
    int d = tid & 63, g = tid >> 6;
    float a = 0.f;
    for (int kk = g; kk < kc; kk += 4)
        a += sp[kk] * qkv[(size_t)(klo + kk) * 1536 + 1024 + h * 64 + d];
    pacc[g][d] = a;
    __syncthreads();
    if (tid < 64) {
        float r = (pacc[0][tid] + pacc[1][tid] + pacc[2][tid] + pacc[3][tid]) * inv;
        o[(size_t)t * 512 + h * 64 + tid] = r;
    }
}

// ---------------- causal 1D conv ----------------
template <int KK, bool ELU_IN, bool ACC>
__global__ __launch_bounds__(256) void conv1d(const float* __restrict__ x,
    const float* __restrict__ w, const float* __restrict__ bias,
    float* __restrict__ y, int Ci, int T)
{
    __shared__ float ws_w[3584];  // max Ci*KK = 512*7
    int co = blockIdx.y;
    int t = blockIdx.x * 256 + threadIdx.x;
    for (int i = threadIdx.x; i < Ci * KK; i += 256)
        ws_w[i] = w[(size_t)co * Ci * KK + i];
    __syncthreads();
    if (t >= T) return;
    float acc = bias[co];
    for (int ci = 0; ci < Ci; ci++) {
        const float* xr = x + (size_t)ci * T;
#pragma unroll
        for (int j = 0; j < KK; j++) {
            int tt = t - (KK - 1) + j;
            float v = (tt >= 0) ? xr[tt] : 0.f;
            if (ELU_IN) v = v > 0.f ? v : __expf(v) - 1.f;
            acc += ws_w[ci * KK + j] * v;
        }
    }
    size_t idx = (size_t)co * T + t;
    if (ACC) y[idx] += acc; else y[idx] = acc;
}

// ---------------- transposed conv, k = 2s (exactly two taps per output) ------
template <int SS, int KK>
__global__ __launch_bounds__(256) void convtr1d(const float* __restrict__ x,
    const float* __restrict__ w, const float* __restrict__ bias,
    float* __restrict__ y, int Ci, int Co, int Ti, int To)
{
    __shared__ float ws_w[512 * KK];
    int co = blockIdx.y;
    int to = blockIdx.x * 256 + threadIdx.x;
    bool valid = to < To;
    int ti0 = valid ? to / SS : 0;
    int p = valid ? to - ti0 * SS : 0;
    bool h0 = ti0 < Ti;
    bool h1 = ti0 >= 1;
    float acc = 0.f;
    for (int c0 = 0; c0 < Ci; c0 += 512) {
        int cc = Ci - c0; if (cc > 512) cc = 512;
        __syncthreads();
        for (int i = threadIdx.x; i < cc * KK; i += 256) {
            int ci = i / KK, kk = i - ci * KK;
            ws_w[i] = w[((size_t)(c0 + ci) * Co + co) * KK + kk];
        }
        __syncthreads();
        if (valid) {
            for (int ci = 0; ci < cc; ci++) {
                float a0 = h0 ? x[(size_t)(c0 + ci) * Ti + ti0] : 0.f;
                float a1 = h1 ? x[(size_t)(c0 + ci) * Ti + ti0 - 1] : 0.f;
                acc += ws_w[ci * KK + p] * a0;
                acc += ws_w[ci * KK + p + SS] * a1;
            }
        }
    }
    if (valid) y[(size_t)co * To + to] = acc + bias[co];
}

// ---------------- stage-4 chunked kernels (Ci=128 -> 64 -> 32 -> out) --------
// z4c layout: [64][LE_MAX], local time tl corresponds to global to = ext0 + tl.
__global__ __launch_bounds__(256) void convtr4_chunk(const float* __restrict__ x,
    const float* __restrict__ w, const float* __restrict__ bias,
    float* __restrict__ y, int ext0, int Le)
{
    __shared__ float ws_w[128 * 8];
    int co = blockIdx.y;                 // 0..63
    int tl = blockIdx.x * 256 + threadIdx.x;
    for (int i = threadIdx.x; i < 128 * 8; i += 256) {
        int ci = i >> 3, kk = i & 7;
        ws_w[i] = w[((size_t)ci * 64 + co) * 8 + kk];
    }
    __syncthreads();
    if (tl >= Le) return;
    int to = ext0 + tl;
    int ti0 = to >> 2, p = to & 3;
    bool h0 = ti0 < T_S3;
    bool h1 = ti0 >= 1;
    float acc = bias[co];
    for (int ci = 0; ci < 128; ci++) {
        float a0 = h0 ? x[(size_t)ci * T_S3 + ti0] : 0.f;
        float a1 = h1 ? x[(size_t)ci * T_S3 + ti0 - 1] : 0.f;
        acc += ws_w[ci * 8 + p] * a0;
        acc += ws_w[ci * 8 + p + 4] * a1;
    }
    y[(size_t)co * LE_MAX + tl] = acc;
}

// va[co][tl] = conv3(ELU(z4))[co][ext0+tl]; valid for tl >= (ext0 ? 2 : 0)
__global__ __launch_bounds__(256) void conv3a_chunk(const float* __restrict__ z4c,
    const float* __restrict__ w, const float* __restrict__ bias,
    float* __restrict__ va, int ext0, int Le)
{
    __shared__ float ws_w[64 * 3];
    int co = blockIdx.y;                 // 0..31
    int tl = blockIdx.x * 256 + threadIdx.x;
    for (int i = threadIdx.x; i < 64 * 3; i += 256)
        ws_w[i] = w[(size_t)co * 192 + i];
    __syncthreads();
    if (tl >= Le) return;
    int vlo = ext0 ? 2 : 0;
    if (tl < vlo) { va[(size_t)co * LE_MAX + tl] = 0.f; return; }
    float acc = bias[co];
    for (int ci = 0; ci < 64; ci++) {
        const float* xr = z4c + (size_t)ci * LE_MAX;
#pragma unroll
        for (int j = 0; j < 3; j++) {
            int tt = tl - 2 + j;
            float v = 0.f;
            if (tt >= 0) {             // ext0==0: global causal zero-pad; ext0>0: tl>=2 so tt>=0
                v = xr[tt];
                v = v > 0.f ? v : __expf(v) - 1.f;
            }
            acc += ws_w[ci * 3 + j] * v;
        }
    }
    va[(size_t)co * LE_MAX + tl] = acc;
}

// z4c[co][tl] += conv1(ELU(va))[co][tl]  (residual), valid tl in [vlo, Le)
__global__ __launch_bounds__(256) void conv1b_chunk(const float* __restrict__ va,
    const float* __restrict__ w, const float* __restrict__ bias,
    float* __restrict__ z4c, int ext0, int Le)
{
    __shared__ float ws_w[32];
    int co = blockIdx.y;                 // 0..63
    int tl = blockIdx.x * 256 + threadIdx.x;
    if (threadIdx.x < 32) ws_w[threadIdx.x] = w[co * 32 + threadIdx.x];
    __syncthreads();
    int vlo = ext0 ? 2 : 0;
    if (tl < vlo || tl >= Le) return;
    float acc = bias[co];
    for (int ci = 0; ci < 32; ci++) {
        float v = va[(size_t)ci * LE_MAX + tl];
        v = v > 0.f ? v : __expf(v) - 1.f;
        acc += ws_w[ci] * v;
    }
    z4c[(size_t)co * LE_MAX + tl] += acc;
}

// out[t0+tl] = conv7(ELU(z4'))[t0+tl] for tl in [0, cnt)
__global__ __launch_bounds__(256) void conv7_out_chunk(const float* __restrict__ z4c,
    const float* __restrict__ w, const float* __restrict__ bias,
    float* __restrict__ out, int ext0, int t0, int cnt)
{
    __shared__ float ws_w[64 * 7];
    int tl = blockIdx.x * 256 + threadIdx.x;
    for (int i = threadIdx.x; i < 448; i += 256) ws_w[i] = w[i];
    __syncthreads();
    if (tl >= cnt) return;
    int t = t0 + tl;
    float acc = bias[0];
    for (int ci = 0; ci < 64; ci++) {
        const float* xr = z4c + (size_t)ci * LE_MAX;
#pragma unroll
        for (int j = 0; j < 7; j++) {
            int tg = t - 6 + j;
            float v = 0.f;
            if (tg >= 0) {
                float z = xr[tg - ext0];
                v = z > 0.f ? z : __expf(z) - 1.f;
            }
            acc += ws_w[ci * 7 + j] * v;
        }
    }
    out[t] = acc;
}

// ---------------- host ----------------
static inline int cdiv(int a, int b) { return (a + b - 1) / b; }

extern "C" void kernel_launch(void* const* d_in, const int* in_sizes, int n_in,
                              void* d_out, int out_size, void* d_ws, size_t ws_size,
                              hipStream_t stream)
{
    const float* latent  = (const float*)d_in[0];
    const float* emb_std = (const float*)d_in[1];
    const float* emb_mean= (const float*)d_in[2];
    const float* quant_w = (const float*)d_in[3];
    const float* quant_b = (const float*)d_in[4];
    const float* up_w    = (const float*)d_in[5];
    const float* up_b    = (const float*)d_in[6];
    const float* n1w     = (const float*)d_in[7];
    const float* n1b     = (const float*)d_in[8];
    const float* ipw     = (const float*)d_in[9];
    const float* ipb     = (const float*)d_in[10];
    const float* opw     = (const float*)d_in[11];
    const float* opb     = (const float*)d_in[12];
    const float* ls1     = (const float*)d_in[13];
    const float* n2w     = (const float*)d_in[14];
    const float* n2b     = (const float*)d_in[15];
    const float* l1w     = (const float*)d_in[16];
    const float* l1b     = (const float*)d_in[17];
    const float* l2w     = (const float*)d_in[18];
    const float* l2b     = (const float*)d_in[19];
    const float* ls2     = (const float*)d_in[20];
    const float* tproj_w = (const float*)d_in[21];
    const float* tproj_b = (const float*)d_in[22];
    const float* dc0_w   = (const float*)d_in[23];
    const float* dc0_b   = (const float*)d_in[24];
    const float* df_w    = (const float*)d_in[49];
    const float* df_b    = (const float*)d_in[50];

    float* W = (float*)d_ws;
    float* OUT = (float*)d_out;

    // ---- frontend ----
    embed_k<<<cdiv(512 * 512, 256), 256, 0, stream>>>(latent, emb_std, emb_mean, W + O_X0);
    conv1d<1, false, false><<<dim3(2, 512), 256, 0, stream>>>(W + O_X0, quant_w, quant_b, W + O_XQ, 512, 512);
    convtr1d<2, 4><<<dim3(cdiv(TT, 256), 512), 256, 0, stream>>>(W + O_XQ, up_w, up_b, W + O_XU, 512, 512, 512, TT);
    transpose_k<<<dim3(cdiv(TT, 32), cdiv(512, 32)), 256, 0, stream>>>(W + O_XU, W + O_Z, 512, TT);
    rope_tables<<<cdiv(TT * 32, 256), 256, 0, stream>>>(W + O_COS, W + O_SIN);

    // ---- transformer ----
    for (int l = 0; l < 8; l++) {
        ln_kernel<<<TT, 256, 0, stream>>>(W + O_Z, n1w + l * 512, n1b + l * 512, W + O_HN);
        gemm_nt<0><<<dim3(1536 / 64, cdiv(TT, 64)), 256, 0, stream>>>(
            W + O_HN, ipw + (size_t)l * 1536 * 512, ipb + l * 1536, nullptr, W + O_QKV, TT, 1536, 512);
        rope_apply<<<cdiv(TT * 8 * 32, 256), 256, 0, stream>>>(W + O_QKV, W + O_COS, W + O_SIN);
        attn_kernel<<<dim3(TT, 8), 256, 0, stream>>>(W + O_QKV, W + O_AO);
        gemm_nt<2><<<dim3(512 / 64, cdiv(TT, 64)), 256, 0, stream>>>(
            W + O_AO, opw + (size_t)l * 512 * 512, opb + l * 512, ls1 + l * 512, W + O_Z, TT, 512, 512);
        ln_kernel<<<TT, 256, 0, stream>>>(W + O_Z, n2w + l * 512, n2b + l * 512, W + O_HN);
        gemm_nt<1><<<dim3(2048 / 64, cdiv(TT, 64)), 256, 0, stream>>>(
            W + O_HN, l1w + (size_t)l * 2048 * 512, l1b + l * 2048, nullptr, W + O_FF, TT, 2048, 512);
        gemm_nt<2><<<dim3(512 / 64, cdiv(TT, 64)), 256, 0, stream>>>(
            W + O_FF, l2w + (size_t)l * 512 * 2048, l2b + l * 512, ls2 + l * 512, W + O_Z, TT, 512, 2048);
    }

    // ---- back to conv domain ----
    gemm_nt<0><<<dim3(512 / 64, cdiv(TT, 64)), 256, 0, stream>>>(
        W + O_Z, tproj_w, tproj_b, nullptr, W + O_ZT, TT, 512, 512);
    transpose_k<<<dim3(cdiv(512, 32), cdiv(TT, 32)), 256, 0, stream>>>(W + O_ZT, W + O_ZC, TT, 512);
    conv1d<7, false, false><<<dim3(cdiv(TT, 256), 1024), 256, 0, stream>>>(
        W + O_ZC, dc0_w, dc0_b, W + O_D0, 512, TT);

    // ---- upsample stage 1: 1024 -> 512, s=8 ----
    {
        const float* tw = (const float*)d_in[25]; const float* tb = (const float*)d_in[26];
        const float* raw = (const float*)d_in[27]; const float* rab = (const float*)d_in[28];
        const float* rbw = (const float*)d_in[29]; const float* rbb = (const float*)d_in[30];
        elu_ip<<<cdiv(1024 * TT, 256), 256, 0, stream>>>(W + O_D0, 1024 * TT);
        convtr1d<8, 16><<<dim3(cdiv(T_S1, 256), 512), 256, 0, stream>>>(
            W + O_D0, tw, tb, W + O_Z1, 1024, 512, TT, T_S1);
        conv1d<3, true, false><<<dim3(cdiv(T_S1, 256), 256), 256, 0, stream>>>(
            W + O_Z1, raw, rab, W + O_V1, 512, T_S1);
        elu_ip<<<cdiv(256 * T_S1, 256), 256, 0, stream>>>(W + O_V1, 256 * T_S1);
        conv1d<1, false, true><<<dim3(cdiv(T_S1, 256), 512), 256, 0, stream>>>(
            W + O_V1, rbw, rbb, W + O_Z1, 256, T_S1);
    }
    // ---- stage 2: 512 -> 256, s=6 ----
    {
        const float* tw = (const float*)d_in[31]; const float* tb = (const float*)d_in[32];
        const float* raw = (const float*)d_in[33]; const float* rab = (const float*)d_in[34];
        const float* rbw = (const float*)d_in[35]; const float* rbb = (const float*)d_in[36];
        elu_ip<<<cdiv(512 * T_S1, 256), 256, 0, stream>>>(W + O_Z1, 512 * T_S1);
        convtr1d<6, 12><<<dim3(cdiv(T_S2, 256), 256), 256, 0, stream>>>(
            W + O_Z1, tw, tb, W + O_Z2, 512, 256, T_S1, T_S2);
        conv1d<3, true, false><<<dim3(cdiv(T_S2, 256), 128), 256, 0, stream>>>(
            W + O_Z2, raw, rab, W + O_V2, 256, T_S2);
        elu_ip<<<cdiv(128 * T_S2, 256), 256, 0, stream>>>(W + O_V2, 128 * T_S2);
        conv1d<1, false, true><<<dim3(cdiv(T_S2, 256), 256), 256, 0, stream>>>(
            W + O_V2, rbw, rbb, W + O_Z2, 128, T_S2);
    }
    // ---- stage 3: 256 -> 128, s=5 ----
    {
        const float* tw = (const float*)d_in[37]; const float* tb = (const float*)d_in[38];
        const float* raw = (const float*)d_in[39]; const float* rab = (const float*)d_in[40];
        const float* rbw = (const float*)d_in[41]; const float* rbb = (const float*)d_in[42];
        elu_ip<<<cdiv(256 * T_S2, 256), 256, 0, stream>>>(W + O_Z2, 256 * T_S2);
        convtr1d<5, 10><<<dim3(cdiv(T_S3, 256), 128), 256, 0, stream>>>(
            W + O_Z2, tw, tb, W + O_Z3, 256, 128, T_S2, T_S3);
        conv1d<3, true, false><<<dim3(cdiv(T_S3, 256), 64), 256, 0, stream>>>(
            W + O_Z3, raw, rab, W + O_V3, 128, T_S3);
        elu_ip<<<cdiv(64 * T_S3, 256), 256, 0, stream>>>(W + O_V3, 64 * T_S3);
        conv1d<1, false, true><<<dim3(cdiv(T_S3, 256), 128), 256, 0, stream>>>(
            W + O_V3, rbw, rbb, W + O_Z3, 64, T_S3);
    }
    // ---- stage 4 (128 -> 64, s=4) + final conv: temporally chunked ----
    {
        const float* tw = (const float*)d_in[43]; const float* tb = (const float*)d_in[44];
        const float* raw = (const float*)d_in[45]; const float* rab = (const float*)d_in[46];
        const float* rbw = (const float*)d_in[47]; const float* rbb = (const float*)d_in[48];
        elu_ip<<<cdiv(128 * T_S3, 256), 256, 0, stream>>>(W + O_Z3, 128 * T_S3);
        for (int c = 0; c < NCH; c++) {
            int t0 = c * LC;
            int ext0 = (c == 0) ? 0 : t0 - 8;
            int Le = t0 + LC - ext0;
            convtr4_chunk<<<dim3(cdiv(Le, 256), 64), 256, 0, stream>>>(
                W + O_Z3, tw, tb, W + O_Z4C, ext0, Le);
            conv3a_chunk<<<dim3(cdiv(Le, 256), 32), 256, 0, stream>>>(
                W + O_Z4C, raw, rab, W + O_VAC, ext0, Le);
            conv1b_chunk<<<dim3(cdiv(Le, 256), 64), 256, 0, stream>>>(
                W + O_VAC, rbw, rbb, W + O_Z4C, ext0, Le);
            conv7_out_chunk<<<dim3(cdiv(LC, 256), 1), 256, 0, stream>>>(
                W + O_Z4C, df_w, df_b, OUT, ext0, t0, LC);
        }
    }
}

// Round 4
// 10941.409 us; speedup vs baseline: 2.5648x; 2.5648x over previous
//
#include <hip/hip_runtime.h>
#include <math.h>

// ---------------- constants ----------------
static constexpr int TT   = 1026;   // transformer length
static constexpr int T_S1 = 8216;
static constexpr int T_S2 = 49302;
static constexpr int T_S3 = 246515;
static constexpr int T_S4 = 986064;

static constexpr int NCH    = 8;                 // stage-4 time chunks
static constexpr int LC     = T_S4 / NCH;        // 123258
static constexpr int LE_MAX = LC + 8;            // chunk + 8-frame halo

// workspace offsets (floats). Peak = 47,330,880 fl = 189.3 MB.
static constexpr size_t O_X0  = 0;
static constexpr size_t O_XQ  = 262144;
static constexpr size_t O_XU  = 524288;    // (512,1026)
static constexpr size_t O_Z   = 1049600;   // (1026,512)
static constexpr size_t O_HN  = 1574912;
static constexpr size_t O_QKV = 2100224;   // (1026,1536)
static constexpr size_t O_AO  = 3676160;   // (1026,512)
static constexpr size_t O_FF  = 4201472;   // (1026,2048)
static constexpr size_t O_COS = 6302720;   // (1026,32)
static constexpr size_t O_SIN = 6335552;
static constexpr size_t O_ZT  = 6368384;   // (1026,512)
static constexpr size_t O_ZC  = 6893696;   // (512,1026)
static constexpr size_t O_D0  = 7419008;   // (1024,1026) ends 8,469,632
static constexpr size_t O_Z1  = 8469632;   // (512,8216)
static constexpr size_t O_V1  = 12676224;  // (256,8216)
static constexpr size_t O_Z2  = 31553920;  // (256,49302)
static constexpr size_t O_V2  = 0;         // (128,49302)
static constexpr size_t O_Z3  = 0;         // (128,246515)
static constexpr size_t O_V3  = 31553920;  // (64,246515)  <-- peak 47,330,880
static constexpr size_t O_Z4C = 31553920;  // (64,LE_MAX)
static constexpr size_t O_VAC = 39442944;  // (32,LE_MAX)

static inline int cdiv(int a, int b) { return (a + b - 1) / b; }

// ---------------- elementwise ----------------
__global__ __launch_bounds__(256) void embed_k(const float* __restrict__ lat,
    const float* __restrict__ sd, const float* __restrict__ mn, float* __restrict__ y)
{
    int i = blockIdx.x * 256 + threadIdx.x;
    if (i >= 512 * 512) return;
    int c = i >> 9;
    y[i] = lat[i] * sd[c] + mn[c];
}

__global__ __launch_bounds__(256) void rope_tables(float* __restrict__ cs, float* __restrict__ sn)
{
    int idx = blockIdx.x * 256 + threadIdx.x;
    if (idx >= TT * 32) return;
    int i = idx & 31;
    int t = idx >> 5;
    float fr = expf(-(float)i * (logf(10000.f) / 32.f));
    float ang = (float)t * fr;
    cs[idx] = cosf(ang);
    sn[idx] = sinf(ang);
}

__global__ __launch_bounds__(256) void rope_apply(float* __restrict__ qkv,
    const float* __restrict__ cs, const float* __restrict__ sn)
{
    int idx = blockIdx.x * 256 + threadIdx.x;
    if (idx >= TT * 8 * 32) return;
    int i = idx & 31;
    int h = (idx >> 5) & 7;
    int t = idx >> 8;
    float c = cs[t * 32 + i], s = sn[t * 32 + i];
    size_t base = (size_t)t * 1536 + h * 64 + 2 * i;
    float re = qkv[base], im = qkv[base + 1];
    qkv[base]     = re * c - im * s;
    qkv[base + 1] = re * s + im * c;
    base += 512;
    re = qkv[base]; im = qkv[base + 1];
    qkv[base]     = re * c - im * s;
    qkv[base + 1] = re * s + im * c;
}

__global__ __launch_bounds__(256) void transpose_k(const float* __restrict__ in,
    float* __restrict__ out, int R, int C)
{
    __shared__ float tile[32][33];
    int c0 = blockIdx.x * 32, r0 = blockIdx.y * 32;
    int tx = threadIdx.x & 31, ty = threadIdx.x >> 5;
    for (int dy = ty; dy < 32; dy += 8) {
        int r = r0 + dy, c = c0 + tx;
        tile[dy][tx] = (r < R && c < C) ? in[(size_t)r * C + c] : 0.f;
    }
    __syncthreads();
    for (int dy = ty; dy < 32; dy += 8) {
        int c = c0 + dy, r = r0 + tx;
        if (c < C && r < R) out[(size_t)c * R + r] = tile[tx][dy];
    }
}

// ---------------- layernorm ----------------
__global__ __launch_bounds__(256) void ln_kernel(const float* __restrict__ x,
    const float* __restrict__ w, const float* __restrict__ b, float* __restrict__ y)
{
    int t = blockIdx.x, tid = threadIdx.x;
    const float* xr = x + (size_t)t * 512;
    float v0 = xr[tid], v1 = xr[tid + 256];
    float s = v0 + v1, q = v0 * v0 + v1 * v1;
    for (int off = 32; off; off >>= 1) {
        s += __shfl_down(s, off);
        q += __shfl_down(q, off);
    }
    __shared__ float ss[4], qq[4], mb[2];
    int wid = tid >> 6, lane = tid & 63;
    if (lane == 0) { ss[wid] = s; qq[wid] = q; }
    __syncthreads();
    if (tid == 0) {
        float S = ss[0] + ss[1] + ss[2] + ss[3];
        float Q = qq[0] + qq[1] + qq[2] + qq[3];
        float m = S * (1.f / 512.f);
        float var = Q * (1.f / 512.f) - m * m;
        mb[0] = m;
        mb[1] = rsqrtf(var + 1e-5f);
    }
    __syncthreads();
    float m = mb[0], inv = mb[1];
    y[(size_t)t * 512 + tid]       = (v0 - m) * inv * w[tid] + b[tid];
    y[(size_t)t * 512 + tid + 256] = (v1 - m) * inv * w[tid + 256] + b[tid + 256];
}

// ---------------- NT GEMM ----------------
template <int EPI>
__global__ __launch_bounds__(256) void gemm_nt(const float* __restrict__ A,
    const float* __restrict__ W, const float* __restrict__ bias,
    const float* __restrict__ ls, float* __restrict__ C, int M, int N, int K)
{
    __shared__ float As[16][68];
    __shared__ float Bs[16][68];
    int m0 = blockIdx.y * 64, n0 = blockIdx.x * 64;
    int tid = threadIdx.x;
    int tx = tid & 15, ty = tid >> 4;
    int arow = tid >> 2, acol = (tid & 3) * 4;
    float acc[4][4] = {};
    for (int k0 = 0; k0 < K; k0 += 16) {
        int am = m0 + arow;
        float4 av = make_float4(0.f, 0.f, 0.f, 0.f);
        if (am < M) av = *(const float4*)(A + (size_t)am * K + k0 + acol);
        float4 wv = *(const float4*)(W + (size_t)(n0 + arow) * K + k0 + acol);
        __syncthreads();
        As[acol + 0][arow] = av.x; As[acol + 1][arow] = av.y;
        As[acol + 2][arow] = av.z; As[acol + 3][arow] = av.w;
        Bs[acol + 0][arow] = wv.x; Bs[acol + 1][arow] = wv.y;
        Bs[acol + 2][arow] = wv.z; Bs[acol + 3][arow] = wv.w;
        __syncthreads();
#pragma unroll
        for (int kk = 0; kk < 16; kk++) {
            float4 a = *(const float4*)&As[kk][ty * 4];
            float4 b = *(const float4*)&Bs[kk][tx * 4];
            float aa[4] = {a.x, a.y, a.z, a.w};
            float bb[4] = {b.x, b.y, b.z, b.w};
#pragma unroll
            for (int i = 0; i < 4; i++)
#pragma unroll
                for (int j = 0; j < 4; j++)
                    acc[i][j] += aa[i] * bb[j];
        }
    }
#pragma unroll
    for (int i = 0; i < 4; i++) {
        int m = m0 + ty * 4 + i;
        if (m >= M) break;
#pragma unroll
        for (int j = 0; j < 4; j++) {
            int n = n0 + tx * 4 + j;
            float v = acc[i][j] + bias[n];
            size_t idx = (size_t)m * N + n;
            if (EPI == 0) C[idx] = v;
            else if (EPI == 1) C[idx] = 0.5f * v * (1.f + erff(v * 0.70710678118654752f));
            else C[idx] += ls[n] * v;
        }
    }
}

// ---------------- windowed causal attention ----------------
__global__ __launch_bounds__(256) void attn_kernel(const float* __restrict__ qkv,
    float* __restrict__ o)
{
    int t = blockIdx.x, h = blockIdx.y, tid = threadIdx.x;
    __shared__ float sq[64];
    __shared__ float sp[256];
    __shared__ float red[256];
    __shared__ float pacc[4][64];
    int klo = t - 249; if (klo < 0) klo = 0;
    int kc = t - klo + 1;
    if (tid < 64) sq[tid] = qkv[(size_t)t * 1536 + h * 64 + tid];
    __syncthreads();
    float sval = -3.0e38f;
    if (tid < kc) {
        const float* kr = qkv + (size_t)(klo + tid) * 1536 + 512 + h * 64;
        float d = 0.f;
#pragma unroll 8
        for (int i = 0; i < 64; i++) d += sq[i] * kr[i];
        sval = d * 0.125f;
    }
    red[tid] = sval;
    __syncthreads();
    for (int s2 = 128; s2 > 0; s2 >>= 1) {
        if (tid < s2) red[tid] = fmaxf(red[tid], red[tid + s2]);
        __syncthreads();
    }
    float m = red[0];
    __syncthreads();
    float p = (tid < kc) ? __expf(sval - m) : 0.f;
    sp[tid] = p;
    red[tid] = p;
    __syncthreads();
    for (int s2 = 128; s2 > 0; s2 >>= 1) {
        if (tid < s2) red[tid] += red[tid + s2];
        __syncthreads();
    }
    float inv = 1.f / red[0];
    int d = tid & 63, g = tid >> 6;
    float a = 0.f;
    for (int kk = g; kk < kc; kk += 4)
        a += sp[kk] * qkv[(size_t)(klo + kk) * 1536 + 1024 + h * 64 + d];
    pacc[g][d] = a;
    __syncthreads();
    if (tid < 64) {
        float r = (pacc[0][tid] + pacc[1][tid] + pacc[2][tid] + pacc[3][tid]) * inv;
        o[(size_t)t * 512 + h * 64 + tid] = r;
    }
}

// ---------------- tiled causal conv ----------------
// y[co*Ty + (t - y_t0)] (+)= bias[co] + sum_ci,j w[(co*Ci+ci)*K+j] * f(x[ci*x_str + (t-K+1+j - x_t0)])
// x_str: row stride of x buffer; Tx: valid length bound (gl in [0,Tx)).
// Block tile: 32 co x 128 t. Thread: 4 co x 4 consecutive t. CI-chunked LDS staging.
template <int K, int CIC, bool ELU_IN, bool ACC>
__global__ __launch_bounds__(256) void conv_t(
    const float* __restrict__ x, const float* __restrict__ w,
    const float* __restrict__ bias, float* __restrict__ y,
    int Ci, int Co, int x_str, int Tx, int x_t0, int Ty, int y_t0, int to_lo, int to_hi)
{
    constexpr int TW = 128;
    constexpr int XS = (TW + K - 1 + 3) & ~3;   // padded x row stride (multiple of 4)
    constexpr int NX = (4 + K - 1 + 3) & ~3;    // per-thread x regs (float4 multiple)
    __shared__ float xs[CIC][XS];
    __shared__ float ws[CIC][32 * K];
    int tid = threadIdx.x;
    int lane = tid & 31;
    int cg = tid >> 5;              // 0..7
    int co_l = cg * 4;
    int co0 = blockIdx.y * 32;
    int t_base = to_lo + blockIdx.x * TW;
    float acc[4][4] = {};
    for (int c0 = 0; c0 < Ci; c0 += CIC) {
        __syncthreads();
        for (int i = tid; i < CIC * XS; i += 256) {
            int ci = i / XS, tt = i - ci * XS;
            float v = 0.f;
            if (tt < TW + K - 1) {
                int gl = t_base - (K - 1) + tt - x_t0;
                if (gl >= 0 && gl < Tx) {
                    v = x[(size_t)(c0 + ci) * x_str + gl];
                    if (ELU_IN) v = v > 0.f ? v : __expf(v) - 1.f;
                }
            }
            xs[ci][tt] = v;
        }
        for (int i = tid; i < CIC * 32 * K; i += 256) {
            int ci = i / (32 * K), r = i - ci * (32 * K);
            int c = r / K, j = r - c * K;
            ws[ci][r] = w[((size_t)(co0 + c) * Ci + (c0 + ci)) * K + j];
        }
        __syncthreads();
        for (int ci = 0; ci < CIC; ci++) {
            float xv[NX];
            const float* xr = &xs[ci][lane * 4];
#pragma unroll
            for (int u = 0; u < NX / 4; u++) {
                float4 t4 = *(const float4*)(xr + 4 * u);
                xv[4*u] = t4.x; xv[4*u+1] = t4.y; xv[4*u+2] = t4.z; xv[4*u+3] = t4.w;
            }
            float wall[4 * K];
            const float* wr = &ws[ci][co_l * K];
#pragma unroll
            for (int u = 0; u < K; u++) {
                float4 t4 = *(const float4*)(wr + 4 * u);
                wall[4*u] = t4.x; wall[4*u+1] = t4.y; wall[4*u+2] = t4.z; wall[4*u+3] = t4.w;
            }
#pragma unroll
            for (int c = 0; c < 4; c++)
#pragma unroll
                for (int j = 0; j < K; j++) {
                    float wj = wall[c * K + j];
#pragma unroll
                    for (int r = 0; r < 4; r++)
                        acc[c][r] += wj * xv[r + j];
                }
        }
    }
    int t0 = t_base + lane * 4;
#pragma unroll
    for (int c = 0; c < 4; c++) {
        int co = co0 + co_l + c;
        float b = bias[co];
#pragma unroll
        for (int r = 0; r < 4; r++) {
            int t = t0 + r;
            if (t < to_hi) {
                size_t idx = (size_t)co * Ty + (t - y_t0);
                float v = acc[c][r] + b;
                if (ACC) y[idx] += v; else y[idx] = v;
            }
        }
    }
}

// ---------------- tiled transposed conv, k=2s, phase-decomposed ----------------
// y[co][to] = b[co] + sum_ci w[(ci*Co+co)*2S + p]*x[ci][q] + w[...+p+S]*x[ci][q-1],
//   to = S*q + p. Block: COT co x 64 q x all S phases. Thread: CPT co x 2 q x S phases.
template <int S, int COT, int CIC, bool ELU_IN>
__global__ __launch_bounds__(256) void convtr_t(
    const float* __restrict__ x, const float* __restrict__ w,
    const float* __restrict__ bias, float* __restrict__ y,
    int Ci, int Co, int Ti, int Ty, int y_t0, int to_lo, int to_hi)
{
    constexpr int QW = 64;
    constexpr int CPT = COT / 8;
    __shared__ float xs[CIC][QW + 4];
    __shared__ float ws[CIC][COT * 2 * S];
    int tid = threadIdx.x;
    int lane = tid & 31;
    int cg = tid >> 5;
    int co_l = cg * CPT;
    int co0 = blockIdx.y * COT;
    int q0 = to_lo / S + blockIdx.x * QW;
    float acc[CPT][2][S] = {};
    for (int c0 = 0; c0 < Ci; c0 += CIC) {
        __syncthreads();
        for (int i = tid; i < CIC * (QW + 1); i += 256) {
            int ci = i / (QW + 1), qq = i - ci * (QW + 1);
            int q = q0 - 1 + qq;
            float v = 0.f;
            if (q >= 0 && q < Ti) {
                v = x[(size_t)(c0 + ci) * Ti + q];
                if (ELU_IN) v = v > 0.f ? v : __expf(v) - 1.f;
            }
            xs[ci][qq] = v;
        }
        for (int i = tid; i < CIC * COT * 2 * S; i += 256) {
            int ci = i / (COT * 2 * S), r = i - ci * (COT * 2 * S);
            int c = r / (2 * S), tap = r - c * (2 * S);
            ws[ci][r] = w[((size_t)(c0 + ci) * Co + (co0 + c)) * 2 * S + tap];
        }
        __syncthreads();
        for (int ci = 0; ci < CIC; ci++) {
            float x1a = xs[ci][lane];
            float x0a = xs[ci][lane + 1];
            float x1b = xs[ci][lane + 32];
            float x0b = xs[ci][lane + 33];
            float wall[CPT * 2 * S];
            const float* wr = &ws[ci][co_l * 2 * S];
#pragma unroll
            for (int u = 0; u < (CPT * 2 * S) / 4; u++) {
                float4 t4 = *(const float4*)(wr + 4 * u);
                wall[4*u] = t4.x; wall[4*u+1] = t4.y; wall[4*u+2] = t4.z; wall[4*u+3] = t4.w;
            }
#pragma unroll
            for (int c = 0; c < CPT; c++)
#pragma unroll
                for (int p = 0; p < S; p++) {
                    float w0 = wall[c * 2 * S + p];
                    float w1 = wall[c * 2 * S + p + S];
                    acc[c][0][p] += w0 * x0a + w1 * x1a;
                    acc[c][1][p] += w0 * x0b + w1 * x1b;
                }
        }
    }
#pragma unroll
    for (int c = 0; c < CPT; c++) {
        int co = co0 + co_l + c;
        float b = bias[co];
#pragma unroll
        for (int rep = 0; rep < 2; rep++) {
            int q = q0 + lane + rep * 32;
#pragma unroll
            for (int p = 0; p < S; p++) {
                int to = q * S + p;
                if (to >= to_lo && to < to_hi)
                    y[(size_t)co * Ty + (to - y_t0)] = acc[c][rep][p] + b;
            }
        }
    }
}

// ---------------- final conv (Co=1): dedicated ----------------
__global__ __launch_bounds__(256) void conv7_out_chunk(const float* __restrict__ z4c,
    const float* __restrict__ w, const float* __restrict__ bias,
    float* __restrict__ out, int ext0, int t0, int cnt)
{
    __shared__ float ws_w[64 * 7];
    int tl = blockIdx.x * 256 + threadIdx.x;
    for (int i = threadIdx.x; i < 448; i += 256) ws_w[i] = w[i];
    __syncthreads();
    if (tl >= cnt) return;
    int t = t0 + tl;
    float acc = bias[0];
    for (int ci = 0; ci < 64; ci++) {
        const float* xr = z4c + (size_t)ci * LE_MAX;
#pragma unroll
        for (int j = 0; j < 7; j++) {
            int tg = t - 6 + j;
            float v = 0.f;
            if (tg >= 0) {
                float z = xr[tg - ext0];
                v = z > 0.f ? z : __expf(z) - 1.f;
            }
            acc += ws_w[ci * 7 + j] * v;
        }
    }
    out[t] = acc;
}

// ---------------- host launch helpers ----------------
template <int K, int CIC, bool ELU_IN, bool ACC>
static void conv_launch(const float* x, const float* w, const float* b, float* y,
    int Ci, int Co, int x_str, int Tx, int x_t0, int Ty, int y_t0, int to_lo, int to_hi,
    hipStream_t stream)
{
    dim3 g(cdiv(to_hi - to_lo, 128), Co / 32);
    conv_t<K, CIC, ELU_IN, ACC><<<g, 256, 0, stream>>>(x, w, b, y, Ci, Co, x_str, Tx, x_t0, Ty, y_t0, to_lo, to_hi);
}

template <int S, int COT, int CIC, bool ELU_IN>
static void convtr_launch(const float* x, const float* w, const float* b, float* y,
    int Ci, int Co, int Ti, int Ty, int y_t0, int to_lo, int to_hi, hipStream_t stream)
{
    int q_lo = to_lo / S;
    int nq = (to_hi - 1) / S - q_lo + 1;
    dim3 g(cdiv(nq, 64), Co / COT);
    convtr_t<S, COT, CIC, ELU_IN><<<g, 256, 0, stream>>>(x, w, b, y, Ci, Co, Ti, Ty, y_t0, to_lo, to_hi);
}

extern "C" void kernel_launch(void* const* d_in, const int* in_sizes, int n_in,
                              void* d_out, int out_size, void* d_ws, size_t ws_size,
                              hipStream_t stream)
{
    const float* latent  = (const float*)d_in[0];
    const float* emb_std = (const float*)d_in[1];
    const float* emb_mean= (const float*)d_in[2];
    const float* quant_w = (const float*)d_in[3];
    const float* quant_b = (const float*)d_in[4];
    const float* up_w    = (const float*)d_in[5];
    const float* up_b    = (const float*)d_in[6];
    const float* n1w     = (const float*)d_in[7];
    const float* n1b     = (const float*)d_in[8];
    const float* ipw     = (const float*)d_in[9];
    const float* ipb     = (const float*)d_in[10];
    const float* opw     = (const float*)d_in[11];
    const float* opb     = (const float*)d_in[12];
    const float* ls1     = (const float*)d_in[13];
    const float* n2w     = (const float*)d_in[14];
    const float* n2b     = (const float*)d_in[15];
    const float* l1w     = (const float*)d_in[16];
    const float* l1b     = (const float*)d_in[17];
    const float* l2w     = (const float*)d_in[18];
    const float* l2b     = (const float*)d_in[19];
    const float* ls2     = (const float*)d_in[20];
    const float* tproj_w = (const float*)d_in[21];
    const float* tproj_b = (const float*)d_in[22];
    const float* dc0_w   = (const float*)d_in[23];
    const float* dc0_b   = (const float*)d_in[24];
    const float* df_w    = (const float*)d_in[49];
    const float* df_b    = (const float*)d_in[50];

    float* W = (float*)d_ws;
    float* OUT = (float*)d_out;

    // ---- frontend ----
    embed_k<<<cdiv(512 * 512, 256), 256, 0, stream>>>(latent, emb_std, emb_mean, W + O_X0);
    conv_launch<1, 16, false, false>(W + O_X0, quant_w, quant_b, W + O_XQ,
        512, 512, 512, 512, 0, 512, 0, 0, 512, stream);
    convtr_launch<2, 32, 16, false>(W + O_XQ, up_w, up_b, W + O_XU,
        512, 512, 512, TT, 0, 0, TT, stream);
    transpose_k<<<dim3(cdiv(TT, 32), cdiv(512, 32)), 256, 0, stream>>>(W + O_XU, W + O_Z, 512, TT);
    rope_tables<<<cdiv(TT * 32, 256), 256, 0, stream>>>(W + O_COS, W + O_SIN);

    // ---- transformer ----
    for (int l = 0; l < 8; l++) {
        ln_kernel<<<TT, 256, 0, stream>>>(W + O_Z, n1w + l * 512, n1b + l * 512, W + O_HN);
        gemm_nt<0><<<dim3(1536 / 64, cdiv(TT, 64)), 256, 0, stream>>>(
            W + O_HN, ipw + (size_t)l * 1536 * 512, ipb + l * 1536, nullptr, W + O_QKV, TT, 1536, 512);
        rope_apply<<<cdiv(TT * 8 * 32, 256), 256, 0, stream>>>(W + O_QKV, W + O_COS, W + O_SIN);
        attn_kernel<<<dim3(TT, 8), 256, 0, stream>>>(W + O_QKV, W + O_AO);
        gemm_nt<2><<<dim3(512 / 64, cdiv(TT, 64)), 256, 0, stream>>>(
            W + O_AO, opw + (size_t)l * 512 * 512, opb + l * 512, ls1 + l * 512, W + O_Z, TT, 512, 512);
        ln_kernel<<<TT, 256, 0, stream>>>(W + O_Z, n2w + l * 512, n2b + l * 512, W + O_HN);
        gemm_nt<1><<<dim3(2048 / 64, cdiv(TT, 64)), 256, 0, stream>>>(
            W + O_HN, l1w + (size_t)l * 2048 * 512, l1b + l * 2048, nullptr, W + O_FF, TT, 2048, 512);
        gemm_nt<2><<<dim3(512 / 64, cdiv(TT, 64)), 256, 0, stream>>>(
            W + O_FF, l2w + (size_t)l * 512 * 2048, l2b + l * 512, ls2 + l * 512, W + O_Z, TT, 512, 2048);
    }

    // ---- back to conv domain ----
    gemm_nt<0><<<dim3(512 / 64, cdiv(TT, 64)), 256, 0, stream>>>(
        W + O_Z, tproj_w, tproj_b, nullptr, W + O_ZT, TT, 512, 512);
    transpose_k<<<dim3(cdiv(512, 32), cdiv(TT, 32)), 256, 0, stream>>>(W + O_ZT, W + O_ZC, TT, 512);
    conv_launch<7, 16, false, false>(W + O_ZC, dc0_w, dc0_b, W + O_D0,
        512, 1024, TT, TT, 0, TT, 0, 0, TT, stream);

    // ---- stage 1: 1024 -> 512, s=8 ----
    {
        const float* tw = (const float*)d_in[25]; const float* tb = (const float*)d_in[26];
        const float* raw = (const float*)d_in[27]; const float* rab = (const float*)d_in[28];
        const float* rbw = (const float*)d_in[29]; const float* rbb = (const float*)d_in[30];
        convtr_launch<8, 16, 8, true>(W + O_D0, tw, tb, W + O_Z1,
            1024, 512, TT, T_S1, 0, 0, T_S1, stream);
        conv_launch<3, 16, true, false>(W + O_Z1, raw, rab, W + O_V1,
            512, 256, T_S1, T_S1, 0, T_S1, 0, 0, T_S1, stream);
        conv_launch<1, 16, true, true>(W + O_V1, rbw, rbb, W + O_Z1,
            256, 512, T_S1, T_S1, 0, T_S1, 0, 0, T_S1, stream);
    }
    // ---- stage 2: 512 -> 256, s=6 ----
    {
        const float* tw = (const float*)d_in[31]; const float* tb = (const float*)d_in[32];
        const float* raw = (const float*)d_in[33]; const float* rab = (const float*)d_in[34];
        const float* rbw = (const float*)d_in[35]; const float* rbb = (const float*)d_in[36];
        convtr_launch<6, 32, 8, true>(W + O_Z1, tw, tb, W + O_Z2,
            512, 256, T_S1, T_S2, 0, 0, T_S2, stream);
        conv_launch<3, 16, true, false>(W + O_Z2, raw, rab, W + O_V2,
            256, 128, T_S2, T_S2, 0, T_S2, 0, 0, T_S2, stream);
        conv_launch<1, 16, true, true>(W + O_V2, rbw, rbb, W + O_Z2,
            128, 256, T_S2, T_S2, 0, T_S2, 0, 0, T_S2, stream);
    }
    // ---- stage 3: 256 -> 128, s=5 ----
    {
        const float* tw = (const float*)d_in[37]; const float* tb = (const float*)d_in[38];
        const float* raw = (const float*)d_in[39]; const float* rab = (const float*)d_in[40];
        const float* rbw = (const float*)d_in[41]; const float* rbb = (const float*)d_in[42];
        convtr_launch<5, 32, 8, true>(W + O_Z2, tw, tb, W + O_Z3,
            256, 128, T_S2, T_S3, 0, 0, T_S3, stream);
        conv_launch<3, 16, true, false>(W + O_Z3, raw, rab, W + O_V3,
            128, 64, T_S3, T_S3, 0, T_S3, 0, 0, T_S3, stream);
        conv_launch<1, 16, true, true>(W + O_V3, rbw, rbb, W + O_Z3,
            64, 128, T_S3, T_S3, 0, T_S3, 0, 0, T_S3, stream);
    }
    // ---- stage 4 (128 -> 64, s=4) + final conv: temporally chunked ----
    {
        const float* tw = (const float*)d_in[43]; const float* tb = (const float*)d_in[44];
        const float* raw = (const float*)d_in[45]; const float* rab = (const float*)d_in[46];
        const float* rbw = (const float*)d_in[47]; const float* rbb = (const float*)d_in[48];
        for (int c = 0; c < NCH; c++) {
            int t0 = c * LC;
            int ext0 = (c == 0) ? 0 : t0 - 8;
            int Le = t0 + LC - ext0;
            int vlo = (c == 0) ? 0 : ext0 + 2;   // first t with valid residual path
            convtr_launch<4, 32, 16, true>(W + O_Z3, tw, tb, W + O_Z4C,
                128, 64, T_S3, LE_MAX, ext0, ext0, ext0 + Le, stream);
            // NOTE: chunk buffers have row stride LE_MAX; valid length Le (differs for chunk 0).
            conv_launch<3, 16, true, false>(W + O_Z4C, raw, rab, W + O_VAC,
                64, 32, LE_MAX, Le, ext0, LE_MAX, ext0, vlo, ext0 + Le, stream);
            conv_launch<1, 16, true, true>(W + O_VAC, rbw, rbb, W + O_Z4C,
                32, 64, LE_MAX, Le, ext0, LE_MAX, ext0, vlo, ext0 + Le, stream);
            conv7_out_chunk<<<dim3(cdiv(LC, 256), 1), 256, 0, stream>>>(
                W + O_Z4C, df_w, df_b, OUT, ext0, t0, LC);
        }
    }
}

// Round 5
// 7886.235 us; speedup vs baseline: 3.5584x; 1.3874x over previous
//
#include <hip/hip_runtime.h>
#include <math.h>

typedef __attribute__((ext_vector_type(8))) short short8;
typedef __attribute__((ext_vector_type(4))) float f32x4;

#define MFMA16(a, b, c) __builtin_amdgcn_mfma_f32_16x16x32_bf16((a), (b), (c), 0, 0, 0)

__device__ __forceinline__ unsigned bfu(float f) {
    unsigned u = __float_as_uint(f);
    return (u + 0x7fffu + ((u >> 16) & 1u)) >> 16;   // RNE fp32->bf16
}

// ---------------- constants ----------------
static constexpr int TT   = 1026;
static constexpr int T_S1 = 8216;
static constexpr int T_S2 = 49302;
static constexpr int T_S3 = 246515;
static constexpr int T_S4 = 986064;

static constexpr int NCH    = 8;
static constexpr int LC     = T_S4 / NCH;        // 123258
static constexpr int LE_MAX = LC + 8;

// workspace offsets (floats). Peak 189.3 MB (unchanged from R4-pass).
static constexpr size_t O_X0  = 0;
static constexpr size_t O_XQ  = 262144;
static constexpr size_t O_XU  = 524288;
static constexpr size_t O_Z   = 1049600;
static constexpr size_t O_HN  = 1574912;
static constexpr size_t O_QKV = 2100224;
static constexpr size_t O_AO  = 3676160;
static constexpr size_t O_FF  = 4201472;
static constexpr size_t O_COS = 6302720;
static constexpr size_t O_SIN = 6335552;
static constexpr size_t O_ZT  = 6368384;
static constexpr size_t O_ZC  = 6893696;
static constexpr size_t O_D0  = 7419008;
static constexpr size_t O_Z1  = 8469632;
static constexpr size_t O_V1  = 12676224;
static constexpr size_t O_Z2  = 31553920;
static constexpr size_t O_V2  = 0;
static constexpr size_t O_Z3  = 0;
static constexpr size_t O_V3  = 31553920;
static constexpr size_t O_Z4C = 31553920;
static constexpr size_t O_VAC = 39442944;

static inline int cdiv(int a, int b) { return (a + b - 1) / b; }

// ---------------- elementwise / small fp32 kernels (unchanged) ----------------
__global__ __launch_bounds__(256) void embed_k(const float* __restrict__ lat,
    const float* __restrict__ sd, const float* __restrict__ mn, float* __restrict__ y)
{
    int i = blockIdx.x * 256 + threadIdx.x;
    if (i >= 512 * 512) return;
    int c = i >> 9;
    y[i] = lat[i] * sd[c] + mn[c];
}

__global__ __launch_bounds__(256) void rope_tables(float* __restrict__ cs, float* __restrict__ sn)
{
    int idx = blockIdx.x * 256 + threadIdx.x;
    if (idx >= TT * 32) return;
    int i = idx & 31;
    int t = idx >> 5;
    float fr = expf(-(float)i * (logf(10000.f) / 32.f));
    float ang = (float)t * fr;
    cs[idx] = cosf(ang);
    sn[idx] = sinf(ang);
}

__global__ __launch_bounds__(256) void rope_apply(float* __restrict__ qkv,
    const float* __restrict__ cs, const float* __restrict__ sn)
{
    int idx = blockIdx.x * 256 + threadIdx.x;
    if (idx >= TT * 8 * 32) return;
    int i = idx & 31;
    int h = (idx >> 5) & 7;
    int t = idx >> 8;
    float c = cs[t * 32 + i], s = sn[t * 32 + i];
    size_t base = (size_t)t * 1536 + h * 64 + 2 * i;
    float re = qkv[base], im = qkv[base + 1];
    qkv[base]     = re * c - im * s;
    qkv[base + 1] = re * s + im * c;
    base += 512;
    re = qkv[base]; im = qkv[base + 1];
    qkv[base]     = re * c - im * s;
    qkv[base + 1] = re * s + im * c;
}

__global__ __launch_bounds__(256) void transpose_k(const float* __restrict__ in,
    float* __restrict__ out, int R, int C)
{
    __shared__ float tile[32][33];
    int c0 = blockIdx.x * 32, r0 = blockIdx.y * 32;
    int tx = threadIdx.x & 31, ty = threadIdx.x >> 5;
    for (int dy = ty; dy < 32; dy += 8) {
        int r = r0 + dy, c = c0 + tx;
        tile[dy][tx] = (r < R && c < C) ? in[(size_t)r * C + c] : 0.f;
    }
    __syncthreads();
    for (int dy = ty; dy < 32; dy += 8) {
        int c = c0 + dy, r = r0 + tx;
        if (c < C && r < R) out[(size_t)c * R + r] = tile[tx][dy];
    }
}

__global__ __launch_bounds__(256) void ln_kernel(const float* __restrict__ x,
    const float* __restrict__ w, const float* __restrict__ b, float* __restrict__ y)
{
    int t = blockIdx.x, tid = threadIdx.x;
    const float* xr = x + (size_t)t * 512;
    float v0 = xr[tid], v1 = xr[tid + 256];
    float s = v0 + v1, q = v0 * v0 + v1 * v1;
    for (int off = 32; off; off >>= 1) {
        s += __shfl_down(s, off);
        q += __shfl_down(q, off);
    }
    __shared__ float ss[4], qq[4], mb[2];
    int wid = tid >> 6, lane = tid & 63;
    if (lane == 0) { ss[wid] = s; qq[wid] = q; }
    __syncthreads();
    if (tid == 0) {
        float S = ss[0] + ss[1] + ss[2] + ss[3];
        float Q = qq[0] + qq[1] + qq[2] + qq[3];
        float m = S * (1.f / 512.f);
        float var = Q * (1.f / 512.f) - m * m;
        mb[0] = m;
        mb[1] = rsqrtf(var + 1e-5f);
    }
    __syncthreads();
    float m = mb[0], inv = mb[1];
    y[(size_t)t * 512 + tid]       = (v0 - m) * inv * w[tid] + b[tid];
    y[(size_t)t * 512 + tid + 256] = (v1 - m) * inv * w[tid + 256] + b[tid + 256];
}

__global__ __launch_bounds__(256) void attn_kernel(const float* __restrict__ qkv,
    float* __restrict__ o)
{
    int t = blockIdx.x, h = blockIdx.y, tid = threadIdx.x;
    __shared__ float sq[64];
    __shared__ float sp[256];
    __shared__ float red[256];
    __shared__ float pacc[4][64];
    int klo = t - 249; if (klo < 0) klo = 0;
    int kc = t - klo + 1;
    if (tid < 64) sq[tid] = qkv[(size_t)t * 1536 + h * 64 + tid];
    __syncthreads();
    float sval = -3.0e38f;
    if (tid < kc) {
        const float* kr = qkv + (size_t)(klo + tid) * 1536 + 512 + h * 64;
        float d = 0.f;
#pragma unroll 8
        for (int i = 0; i < 64; i++) d += sq[i] * kr[i];
        sval = d * 0.125f;
    }
    red[tid] = sval;
    __syncthreads();
    for (int s2 = 128; s2 > 0; s2 >>= 1) {
        if (tid < s2) red[tid] = fmaxf(red[tid], red[tid + s2]);
        __syncthreads();
    }
    float m = red[0];
    __syncthreads();
    float p = (tid < kc) ? __expf(sval - m) : 0.f;
    sp[tid] = p;
    red[tid] = p;
    __syncthreads();
    for (int s2 = 128; s2 > 0; s2 >>= 1) {
        if (tid < s2) red[tid] += red[tid + s2];
        __syncthreads();
    }
    float inv = 1.f / red[0];
    int d = tid & 63, g = tid >> 6;
    float a = 0.f;
    for (int kk = g; kk < kc; kk += 4)
        a += sp[kk] * qkv[(size_t)(klo + kk) * 1536 + 1024 + h * 64 + d];
    pacc[g][d] = a;
    __syncthreads();
    if (tid < 64) {
        float r = (pacc[0][tid] + pacc[1][tid] + pacc[2][tid] + pacc[3][tid]) * inv;
        o[(size_t)t * 512 + h * 64 + tid] = r;
    }
}

// ---------------- MFMA GEMM: C[m,n] = sum_k A[m,k]*Wt[n,k] ----------------
// Block 128x128, BK=64, waves 2x2 of 64x64 (4x4 C-frags). fp32->bf16 at staging.
// EPI 0: C=acc+b ; 1: C=gelu(acc+b) ; 2: C += ls[n]*(acc+b)
template <int EPI>
__global__ __launch_bounds__(256, 3) void mfma_gemm(const float* __restrict__ A,
    const float* __restrict__ Wt, const float* __restrict__ bias,
    const float* __restrict__ ls, float* __restrict__ C, int M, int N, int K)
{
    constexpr int STR = 72;   // u16 stride (144B, 16B-aligned)
    __shared__ unsigned short sA[128 * STR];
    __shared__ unsigned short sB[128 * STR];
    int tid = threadIdx.x;
    int m0 = blockIdx.y * 128, n0 = blockIdx.x * 128;
    int w = tid >> 6, lane = tid & 63;
    int wm = (w >> 1) * 64, wn = (w & 1) * 64;
    int row15 = lane & 15, q8 = (lane >> 4) * 8;
    f32x4 acc[4][4] = {};
    for (int k0 = 0; k0 < K; k0 += 64) {
        __syncthreads();
        for (int i = tid; i < 1024; i += 256) {
            int r = i >> 3, sg = (i & 7) * 8;
            // A rows (guard M)
            unsigned u0 = 0, u1 = 0, u2 = 0, u3 = 0;
            int gm = m0 + r;
            if (gm < M) {
                const float* p = A + (size_t)gm * K + k0 + sg;
                float4 f0 = *(const float4*)p, f1 = *(const float4*)(p + 4);
                u0 = bfu(f0.x) | (bfu(f0.y) << 16); u1 = bfu(f0.z) | (bfu(f0.w) << 16);
                u2 = bfu(f1.x) | (bfu(f1.y) << 16); u3 = bfu(f1.z) | (bfu(f1.w) << 16);
            }
            unsigned* d = (unsigned*)&sA[r * STR + sg];
            d[0] = u0; d[1] = u1; d[2] = u2; d[3] = u3;
            // B rows (guard N)
            u0 = u1 = u2 = u3 = 0;
            int gn = n0 + r;
            if (gn < N) {
                const float* p = Wt + (size_t)gn * K + k0 + sg;
                float4 f0 = *(const float4*)p, f1 = *(const float4*)(p + 4);
                u0 = bfu(f0.x) | (bfu(f0.y) << 16); u1 = bfu(f0.z) | (bfu(f0.w) << 16);
                u2 = bfu(f1.x) | (bfu(f1.y) << 16); u3 = bfu(f1.z) | (bfu(f1.w) << 16);
            }
            d = (unsigned*)&sB[r * STR + sg];
            d[0] = u0; d[1] = u1; d[2] = u2; d[3] = u3;
        }
        __syncthreads();
#pragma unroll
        for (int kk = 0; kk < 64; kk += 32) {
            short8 af[4], bf[4];
#pragma unroll
            for (int f = 0; f < 4; f++) {
                af[f] = *(const short8*)&sA[(wm + f * 16 + row15) * STR + kk + q8];
                bf[f] = *(const short8*)&sB[(wn + f * 16 + row15) * STR + kk + q8];
            }
#pragma unroll
            for (int i = 0; i < 4; i++)
#pragma unroll
                for (int j = 0; j < 4; j++)
                    acc[i][j] = MFMA16(af[i], bf[j], acc[i][j]);
        }
    }
    int rq = (lane >> 4) * 4;
#pragma unroll
    for (int i = 0; i < 4; i++) {
#pragma unroll
        for (int r = 0; r < 4; r++) {
            int m = m0 + wm + i * 16 + rq + r;
            if (m >= M) continue;
#pragma unroll
            for (int j = 0; j < 4; j++) {
                int n = n0 + wn + j * 16 + row15;
                float v = acc[i][j][r] + bias[n];
                size_t idx = (size_t)m * N + n;
                if (EPI == 0) C[idx] = v;
                else if (EPI == 1) C[idx] = 0.5f * v * (1.f + erff(v * 0.70710678118654752f));
                else C[idx] += ls[n] * v;
            }
        }
    }
}

// ---------------- MFMA causal conv (k taps) ----------------
// y[co, t] (+)= b[co] + sum_{ci,j} w[co,ci,j] * f(x[ci, t-(K-1)+j])
// Block tile 64co x 128t; waves 2x2 (wave 32co x 64t). ci-chunks of 32 (=MFMA K).
template <int K, bool ELU_IN, bool ACC>
__global__ __launch_bounds__(256, 3) void mfma_conv(
    const float* __restrict__ x, const float* __restrict__ w,
    const float* __restrict__ bias, float* __restrict__ y,
    int Ci, int Co, int x_str, int Tx, int x_t0, int Ty, int y_t0, int to_lo, int to_hi)
{
    constexpr int TL = 128 + K - 1;
    constexpr int SX = 40;  // u16 stride (80B)
    constexpr int SW = 40;
    __shared__ unsigned short sX[TL * SX];
    __shared__ unsigned short sW[K * 64 * SW];
    int tid = threadIdx.x;
    int co0 = blockIdx.y * 64;
    int t_base = to_lo + blockIdx.x * 128;
    int w_id = tid >> 6, lane = tid & 63;
    int wm = (w_id >> 1) * 32, wn = (w_id & 1) * 64;
    int row15 = lane & 15, q8 = (lane >> 4) * 8;
    f32x4 acc[2][4] = {};
    for (int ci0 = 0; ci0 < Ci; ci0 += 32) {
        __syncthreads();
        // stage x transposed: sX[tl][ci]
        for (int i = tid; i < 32 * TL; i += 256) {
            int ci = i / TL, tl = i - ci * TL;
            int gl = t_base - (K - 1) + tl - x_t0;
            float v = 0.f;
            if (gl >= 0 && gl < Tx) {
                v = x[(size_t)(ci0 + ci) * x_str + gl];
                if (ELU_IN) v = v > 0.f ? v : __expf(v) - 1.f;
            }
            sX[tl * SX + ci] = (unsigned short)bfu(v);
        }
        // stage w: sW[j][co][ci]
        for (int i = tid; i < 64 * 32 * K; i += 256) {
            int co = i / (32 * K), r = i - co * (32 * K);
            int ci = r / K, j = r - ci * K;
            float v = 0.f;
            if (co0 + co < Co)
                v = w[((size_t)(co0 + co) * Ci + ci0 + ci) * K + j];
            sW[(j * 64 + co) * SW + ci] = (unsigned short)bfu(v);
        }
        __syncthreads();
#pragma unroll
        for (int j = 0; j < K; j++) {
            short8 af[2], bf[4];
#pragma unroll
            for (int f = 0; f < 2; f++)
                af[f] = *(const short8*)&sW[(j * 64 + wm + f * 16 + row15) * SW + q8];
#pragma unroll
            for (int f = 0; f < 4; f++)
                bf[f] = *(const short8*)&sX[(wn + f * 16 + row15 + j) * SX + q8];
#pragma unroll
            for (int i = 0; i < 2; i++)
#pragma unroll
                for (int f = 0; f < 4; f++)
                    acc[i][f] = MFMA16(af[i], bf[f], acc[i][f]);
        }
    }
    int rq = (lane >> 4) * 4;
#pragma unroll
    for (int i = 0; i < 2; i++) {
#pragma unroll
        for (int r = 0; r < 4; r++) {
            int co = co0 + wm + i * 16 + rq + r;
            if (co >= Co) continue;
            float b = bias[co];
#pragma unroll
            for (int f = 0; f < 4; f++) {
                int t = t_base + wn + f * 16 + row15;
                if (t < to_hi) {
                    size_t idx = (size_t)co * Ty + (t - y_t0);
                    float v = acc[i][f][r] + b;
                    if (ACC) y[idx] += v; else y[idx] = v;
                }
            }
        }
    }
}

// ---------------- MFMA transposed conv, k=2S, phase-group PG ----------------
// to = q*S + p : y[co,to] = b[co] + sum_ci (w[ci,co,p]*x[ci,q] + w[ci,co,p+S]*x[ci,q-1])
// K-dim = (ci,tap) interleaved: LDS row per q holds [x(q),x(q-1)] pairs for 16 ci.
// Block: 16co x 256q (4 waves a 64q) x PG phases. grid.z = phase group.
template <int S, int PG, bool ELU_IN>
__global__ __launch_bounds__(256, 3) void mfma_convtr(
    const float* __restrict__ x, const float* __restrict__ w,
    const float* __restrict__ bias, float* __restrict__ y,
    int Ci, int Co, int Ti, int Ty, int y_t0, int q_lo, int to_lo, int to_hi)
{
    constexpr int SX = 40;  // u16 stride
    constexpr int SW = 40;
    __shared__ unsigned short sX[256 * SX];
    __shared__ unsigned short sW[PG * 16 * SW];
    int tid = threadIdx.x;
    int co0 = blockIdx.y * 16;
    int q0 = q_lo + blockIdx.x * 256;
    int p0 = blockIdx.z * PG;
    int w_id = tid >> 6, lane = tid & 63;
    int row15 = lane & 15, q8 = (lane >> 4) * 8;
    f32x4 acc[PG][4] = {};
    for (int ci0 = 0; ci0 < Ci; ci0 += 16) {
        __syncthreads();
        // stage x pairs: sX[lq][2ci+tap]
        for (int i = tid; i < 16 * 256; i += 256) {
            int ci = i >> 8, lq = i & 255;
            int q = q0 + lq;
            const float* xr = x + (size_t)(ci0 + ci) * Ti;
            float v0 = 0.f, v1 = 0.f;
            if (q >= 0 && q < Ti) {
                v0 = xr[q];
                if (ELU_IN) v0 = v0 > 0.f ? v0 : __expf(v0) - 1.f;
            }
            if (q - 1 >= 0 && q - 1 < Ti) {
                v1 = xr[q - 1];
                if (ELU_IN) v1 = v1 > 0.f ? v1 : __expf(v1) - 1.f;
            }
            *(unsigned*)&sX[lq * SX + 2 * ci] = bfu(v0) | (bfu(v1) << 16);
        }
        // stage w: sW[p][co][2ci+tap]
        for (int i = tid; i < PG * 512; i += 256) {
            int pl = i >> 9, r = i & 511;
            int co = r >> 5, k = r & 31;
            int ci = k >> 1, tap = k & 1;
            float v = 0.f;
            if (p0 + pl < S)
                v = w[((size_t)(ci0 + ci) * Co + co0 + co) * 2 * S + tap * S + p0 + pl];
            sW[(pl * 16 + co) * SW + k] = (unsigned short)bfu(v);
        }
        __syncthreads();
        short8 bf[4];
#pragma unroll
        for (int f = 0; f < 4; f++)
            bf[f] = *(const short8*)&sX[(w_id * 64 + f * 16 + row15) * SX + q8];
#pragma unroll
        for (int p = 0; p < PG; p++) {
            short8 af = *(const short8*)&sW[(p * 16 + row15) * SW + q8];
#pragma unroll
            for (int f = 0; f < 4; f++)
                acc[p][f] = MFMA16(af, bf[f], acc[p][f]);
        }
    }
    int rq = (lane >> 4) * 4;
#pragma unroll
    for (int r = 0; r < 4; r++) {
        int co = co0 + rq + r;
        float b = bias[co];
#pragma unroll
        for (int f = 0; f < 4; f++) {
            int q = q0 + w_id * 64 + f * 16 + row15;
#pragma unroll
            for (int p = 0; p < PG; p++) {
                int to = q * S + p0 + p;
                if (to >= to_lo && to < to_hi)
                    y[(size_t)co * Ty + (to - y_t0)] = acc[p][f][r] + b;
            }
        }
    }
}

// ---------------- final conv (Co=1), fp32 ----------------
__global__ __launch_bounds__(256) void conv7_out_chunk(const float* __restrict__ z4c,
    const float* __restrict__ w, const float* __restrict__ bias,
    float* __restrict__ out, int ext0, int t0, int cnt)
{
    __shared__ float ws_w[64 * 7];
    int tl = blockIdx.x * 256 + threadIdx.x;
    for (int i = threadIdx.x; i < 448; i += 256) ws_w[i] = w[i];
    __syncthreads();
    if (tl >= cnt) return;
    int t = t0 + tl;
    float acc = bias[0];
    for (int ci = 0; ci < 64; ci++) {
        const float* xr = z4c + (size_t)ci * LE_MAX;
#pragma unroll
        for (int j = 0; j < 7; j++) {
            int tg = t - 6 + j;
            float v = 0.f;
            if (tg >= 0) {
                float z = xr[tg - ext0];
                v = z > 0.f ? z : __expf(z) - 1.f;
            }
            acc += ws_w[ci * 7 + j] * v;
        }
    }
    out[t] = acc;
}

// ---------------- host helpers ----------------
template <int K, bool ELU_IN, bool ACC>
static void conv_launch(const float* x, const float* w, const float* b, float* y,
    int Ci, int Co, int x_str, int Tx, int x_t0, int Ty, int y_t0, int to_lo, int to_hi,
    hipStream_t stream)
{
    dim3 g(cdiv(to_hi - to_lo, 128), cdiv(Co, 64));
    mfma_conv<K, ELU_IN, ACC><<<g, 256, 0, stream>>>(x, w, b, y, Ci, Co, x_str, Tx, x_t0, Ty, y_t0, to_lo, to_hi);
}

template <int S, int PG, bool ELU_IN>
static void convtr_launch(const float* x, const float* w, const float* b, float* y,
    int Ci, int Co, int Ti, int Ty, int y_t0, int to_lo, int to_hi, hipStream_t stream)
{
    int q_lo = to_lo / S;
    int q_hi = (to_hi - 1) / S;
    dim3 g(cdiv(q_hi - q_lo + 1, 256), Co / 16, cdiv(S, PG));
    mfma_convtr<S, PG, ELU_IN><<<g, 256, 0, stream>>>(x, w, b, y, Ci, Co, Ti, Ty, y_t0, q_lo, to_lo, to_hi);
}

extern "C" void kernel_launch(void* const* d_in, const int* in_sizes, int n_in,
                              void* d_out, int out_size, void* d_ws, size_t ws_size,
                              hipStream_t stream)
{
    const float* latent  = (const float*)d_in[0];
    const float* emb_std = (const float*)d_in[1];
    const float* emb_mean= (const float*)d_in[2];
    const float* quant_w = (const float*)d_in[3];
    const float* quant_b = (const float*)d_in[4];
    const float* up_w    = (const float*)d_in[5];
    const float* up_b    = (const float*)d_in[6];
    const float* n1w     = (const float*)d_in[7];
    const float* n1b     = (const float*)d_in[8];
    const float* ipw     = (const float*)d_in[9];
    const float* ipb     = (const float*)d_in[10];
    const float* opw     = (const float*)d_in[11];
    const float* opb     = (const float*)d_in[12];
    const float* ls1     = (const float*)d_in[13];
    const float* n2w     = (const float*)d_in[14];
    const float* n2b     = (const float*)d_in[15];
    const float* l1w     = (const float*)d_in[16];
    const float* l1b     = (const float*)d_in[17];
    const float* l2w     = (const float*)d_in[18];
    const float* l2b     = (const float*)d_in[19];
    const float* ls2     = (const float*)d_in[20];
    const float* tproj_w = (const float*)d_in[21];
    const float* tproj_b = (const float*)d_in[22];
    const float* dc0_w   = (const float*)d_in[23];
    const float* dc0_b   = (const float*)d_in[24];
    const float* df_w    = (const float*)d_in[49];
    const float* df_b    = (const float*)d_in[50];

    float* W = (float*)d_ws;
    float* OUT = (float*)d_out;

    // ---- frontend ----
    embed_k<<<cdiv(512 * 512, 256), 256, 0, stream>>>(latent, emb_std, emb_mean, W + O_X0);
    conv_launch<1, false, false>(W + O_X0, quant_w, quant_b, W + O_XQ,
        512, 512, 512, 512, 0, 512, 0, 0, 512, stream);
    convtr_launch<2, 2, false>(W + O_XQ, up_w, up_b, W + O_XU,
        512, 512, 512, TT, 0, 0, TT, stream);
    transpose_k<<<dim3(cdiv(TT, 32), cdiv(512, 32)), 256, 0, stream>>>(W + O_XU, W + O_Z, 512, TT);
    rope_tables<<<cdiv(TT * 32, 256), 256, 0, stream>>>(W + O_COS, W + O_SIN);

    // ---- transformer ----
    for (int l = 0; l < 8; l++) {
        ln_kernel<<<TT, 256, 0, stream>>>(W + O_Z, n1w + l * 512, n1b + l * 512, W + O_HN);
        mfma_gemm<0><<<dim3(1536 / 128, cdiv(TT, 128)), 256, 0, stream>>>(
            W + O_HN, ipw + (size_t)l * 1536 * 512, ipb + l * 1536, nullptr, W + O_QKV, TT, 1536, 512);
        rope_apply<<<cdiv(TT * 8 * 32, 256), 256, 0, stream>>>(W + O_QKV, W + O_COS, W + O_SIN);
        attn_kernel<<<dim3(TT, 8), 256, 0, stream>>>(W + O_QKV, W + O_AO);
        mfma_gemm<2><<<dim3(512 / 128, cdiv(TT, 128)), 256, 0, stream>>>(
            W + O_AO, opw + (size_t)l * 512 * 512, opb + l * 512, ls1 + l * 512, W + O_Z, TT, 512, 512);
        ln_kernel<<<TT, 256, 0, stream>>>(W + O_Z, n2w + l * 512, n2b + l * 512, W + O_HN);
        mfma_gemm<1><<<dim3(2048 / 128, cdiv(TT, 128)), 256, 0, stream>>>(
            W + O_HN, l1w + (size_t)l * 2048 * 512, l1b + l * 2048, nullptr, W + O_FF, TT, 2048, 512);
        mfma_gemm<2><<<dim3(512 / 128, cdiv(TT, 128)), 256, 0, stream>>>(
            W + O_FF, l2w + (size_t)l * 512 * 2048, l2b + l * 512, ls2 + l * 512, W + O_Z, TT, 512, 2048);
    }

    // ---- back to conv domain ----
    mfma_gemm<0><<<dim3(512 / 128, cdiv(TT, 128)), 256, 0, stream>>>(
        W + O_Z, tproj_w, tproj_b, nullptr, W + O_ZT, TT, 512, 512);
    transpose_k<<<dim3(cdiv(512, 32), cdiv(TT, 32)), 256, 0, stream>>>(W + O_ZT, W + O_ZC, TT, 512);
    conv_launch<7, false, false>(W + O_ZC, dc0_w, dc0_b, W + O_D0,
        512, 1024, TT, TT, 0, TT, 0, 0, TT, stream);

    // ---- stage 1: 1024 -> 512, s=8 ----
    {
        const float* tw = (const float*)d_in[25]; const float* tb = (const float*)d_in[26];
        const float* raw = (const float*)d_in[27]; const float* rab = (const float*)d_in[28];
        const float* rbw = (const float*)d_in[29]; const float* rbb = (const float*)d_in[30];
        convtr_launch<8, 4, true>(W + O_D0, tw, tb, W + O_Z1,
            1024, 512, TT, T_S1, 0, 0, T_S1, stream);
        conv_launch<3, true, false>(W + O_Z1, raw, rab, W + O_V1,
            512, 256, T_S1, T_S1, 0, T_S1, 0, 0, T_S1, stream);
        conv_launch<1, true, true>(W + O_V1, rbw, rbb, W + O_Z1,
            256, 512, T_S1, T_S1, 0, T_S1, 0, 0, T_S1, stream);
    }
    // ---- stage 2: 512 -> 256, s=6 ----
    {
        const float* tw = (const float*)d_in[31]; const float* tb = (const float*)d_in[32];
        const float* raw = (const float*)d_in[33]; const float* rab = (const float*)d_in[34];
        const float* rbw = (const float*)d_in[35]; const float* rbb = (const float*)d_in[36];
        convtr_launch<6, 3, true>(W + O_Z1, tw, tb, W + O_Z2,
            512, 256, T_S1, T_S2, 0, 0, T_S2, stream);
        conv_launch<3, true, false>(W + O_Z2, raw, rab, W + O_V2,
            256, 128, T_S2, T_S2, 0, T_S2, 0, 0, T_S2, stream);
        conv_launch<1, true, true>(W + O_V2, rbw, rbb, W + O_Z2,
            128, 256, T_S2, T_S2, 0, T_S2, 0, 0, T_S2, stream);
    }
    // ---- stage 3: 256 -> 128, s=5 ----
    {
        const float* tw = (const float*)d_in[37]; const float* tb = (const float*)d_in[38];
        const float* raw = (const float*)d_in[39]; const float* rab = (const float*)d_in[40];
        const float* rbw = (const float*)d_in[41]; const float* rbb = (const float*)d_in[42];
        convtr_launch<5, 5, true>(W + O_Z2, tw, tb, W + O_Z3,
            256, 128, T_S2, T_S3, 0, 0, T_S3, stream);
        conv_launch<3, true, false>(W + O_Z3, raw, rab, W + O_V3,
            128, 64, T_S3, T_S3, 0, T_S3, 0, 0, T_S3, stream);
        conv_launch<1, true, true>(W + O_V3, rbw, rbb, W + O_Z3,
            64, 128, T_S3, T_S3, 0, T_S3, 0, 0, T_S3, stream);
    }
    // ---- stage 4 (128 -> 64, s=4) + final conv: temporally chunked ----
    {
        const float* tw = (const float*)d_in[43]; const float* tb = (const float*)d_in[44];
        const float* raw = (const float*)d_in[45]; const float* rab = (const float*)d_in[46];
        const float* rbw = (const float*)d_in[47]; const float* rbb = (const float*)d_in[48];
        for (int c = 0; c < NCH; c++) {
            int t0 = c * LC;
            int ext0 = (c == 0) ? 0 : t0 - 8;
            int Le = t0 + LC - ext0;
            int vlo = (c == 0) ? 0 : ext0 + 2;
            convtr_launch<4, 4, true>(W + O_Z3, tw, tb, W + O_Z4C,
                128, 64, T_S3, LE_MAX, ext0, ext0, ext0 + Le, stream);
            conv_launch<3, true, false>(W + O_Z4C, raw, rab, W + O_VAC,
                64, 32, LE_MAX, Le, ext0, LE_MAX, ext0, vlo, ext0 + Le, stream);
            conv_launch<1, true, true>(W + O_VAC, rbw, rbb, W + O_Z4C,
                32, 64, LE_MAX, Le, ext0, LE_MAX, ext0, vlo, ext0 + Le, stream);
            conv7_out_chunk<<<dim3(cdiv(LC, 256), 1), 256, 0, stream>>>(
                W + O_Z4C, df_w, df_b, OUT, ext0, t0, LC);
        }
    }
}